// Round 13
// baseline (278.599 us; speedup 1.0000x reference)
//
#include <hip/hip_runtime.h>

#define DEVI __device__ __forceinline__

using f32x4 = __attribute__((ext_vector_type(4))) float;
using fvec4 = __attribute__((ext_vector_type(4))) float;
using s16x4 = __attribute__((ext_vector_type(4))) short;
using s16x8 = __attribute__((ext_vector_type(8))) short;

DEVI unsigned short f2bf_rn(float f) {
  union { float f; unsigned u; } v; v.f = f;
  unsigned r = v.u + 0x7fffu + ((v.u >> 16) & 1u);
  return (unsigned short)(r >> 16);
}
DEVI float bf2f(unsigned short h) {
  union { unsigned u; float f; } v; v.u = ((unsigned)h) << 16;
  return v.f;
}
DEVI f32x4 mfma16(s16x8 a, s16x8 b, f32x4 c) {
  return __builtin_amdgcn_mfma_f32_16x16x32_bf16(a, b, c, 0, 0, 0);
}
// async global->LDS, 16B per lane; lds base must be wave-uniform
DEVI void gld16(const void* g, void* lds) {
  __builtin_amdgcn_global_load_lds(
      (const __attribute__((address_space(1))) unsigned int*)g,
      (__attribute__((address_space(3))) unsigned int*)lds, 16, 0, 0);
}

// Fragment-major packing: for MFMA B-operand fragment (fragRow R/16, kChunk
// K0/32), lane l holds row R+(l&15), cols K0+(l>>4)*8..+7. Packed address:
//   P[(frag*32 + kc)*512 + lane*8 + e]
// so a wave's fragment load is 64 lanes x contiguous 16B = 1KB coalesced.

// ------- prep (merged): weights -> fragment-major bf16; omega; X split ------
__global__ __launch_bounds__(256) void k_prep_all(
    const float* __restrict__ wq, const float* __restrict__ wk,
    const float* __restrict__ wv, const float* __restrict__ wo,
    const float* __restrict__ omega, const float* __restrict__ X,
    unsigned short* __restrict__ WFP, unsigned short* __restrict__ WOFP,
    unsigned short* __restrict__ OMB,
    unsigned short* __restrict__ XH, unsigned short* __restrict__ XL)
{
  __shared__ float tile[64][65];
  const int z = blockIdx.z;
  const int t = threadIdx.x;
  if (z >= 5) {  // split X f32 -> bf16 hi/lo
    int s = z - 5;
    int bid = blockIdx.x * 16 + blockIdx.y;
    size_t i = (((size_t)s * 256 + bid) * 256 + t) * 8;
    fvec4 a = *(const fvec4*)&X[i];
    fvec4 b = *(const fvec4*)&X[i + 4];
    s16x8 hv, lv;
#pragma unroll
    for (int j = 0; j < 4; ++j) {
      unsigned short h = f2bf_rn(a[j]);
      hv[j] = (short)h; lv[j] = (short)f2bf_rn(a[j] - bf2f(h));
    }
#pragma unroll
    for (int j = 0; j < 4; ++j) {
      unsigned short h = f2bf_rn(b[j]);
      hv[4 + j] = (short)h; lv[4 + j] = (short)f2bf_rn(b[j] - bf2f(h));
    }
    *(s16x8*)&XH[i] = hv;
    *(s16x8*)&XL[i] = lv;
    return;
  }
  if (z == 4) {  // omega [256][64] f32 -> bf16 linear
    int bid = blockIdx.x * 16 + blockIdx.y;
    if (bid < 16) {
      int i = (bid * 256 + t) * 4;
      fvec4 v = *(const fvec4*)&omega[i];
      s16x4 hv;
#pragma unroll
      for (int q = 0; q < 4; ++q) hv[q] = (short)f2bf_rn(v[q]);
      *(s16x4*)&OMB[i] = hv;
    }
    return;
  }
  const float* src = (z == 0) ? wq : (z == 1) ? wk : (z == 2) ? wv : wo;
  const int k0 = blockIdx.x * 64;
  const int n0 = blockIdx.y * 64;
#pragma unroll
  for (int j = 0; j < 4; ++j) {
    int r = (t >> 4) + 16 * j;
    int c = (t & 15) * 4;
    fvec4 v = *(const fvec4*)&src[(size_t)(k0 + r) * 1024 + n0 + c];
#pragma unroll
    for (int i = 0; i < 4; ++i) tile[r][c + i] = v[i];
  }
  __syncthreads();
#pragma unroll
  for (int j = 0; j < 4; ++j) {
    int n = (t >> 4) + 16 * j;
    int kc = (t & 15) * 4;
    s16x4 hv;
#pragma unroll
    for (int i = 0; i < 4; ++i) hv[i] = (short)f2bf_rn(tile[kc + i][n]);
    const int kk = k0 + kc;
    if (z < 3) {
      int ng = z * 1024 + n0 + n;
      size_t o = ((size_t)((ng >> 4) * 32 + (kk >> 5)) * 512) +
                 (size_t)(((ng & 15) | (((kk >> 3) & 3) << 4)) * 8) + (kk & 7);
      *(s16x4*)&WFP[o] = hv;
    } else {
      int ng = n0 + n;
      size_t o = ((size_t)((ng >> 4) * 32 + (kk >> 5)) * 512) +
                 (size_t)(((ng & 15) | (((kk >> 3) & 3) << 4)) * 8) + (kk & 7);
      *(s16x4*)&WOFP[o] = hv;
    }
  }
}

// ------- QKV GEMM: BN=256 (acc 4x8), A via 2-deep LDS dbuf, B frag-major ----
// cb<8: q,k (2-pass A-split); cb>=8: v. 64 MFMA/wave/K-step (tp).
__global__ __launch_bounds__(256) void k_gemm_qkv(
    const unsigned short* __restrict__ XH, const unsigned short* __restrict__ XL,
    const unsigned short* __restrict__ WFP,
    unsigned short* __restrict__ QH, unsigned short* __restrict__ QL,
    unsigned short* __restrict__ KH, unsigned short* __restrict__ KL,
    unsigned short* __restrict__ VB)
{
  __shared__ unsigned short AH[2][128 * 32];
  __shared__ unsigned short AL[2][128 * 32];
  const int flat = blockIdx.y * 12 + blockIdx.x;   // 0..767
  const int swz = (flat & 7) * 96 + (flat >> 3);   // bijective, 768 % 8 == 0
  const int cb = swz % 12;
  const int rb = swz / 12;
  const int t = threadIdx.x;
  const int w = t >> 6, l = t & 63;
  const bool tp = (cb < 8);
  f32x4 acc[4][8];
#pragma unroll
  for (int a = 0; a < 4; ++a)
#pragma unroll
    for (int b = 0; b < 8; ++b) acc[a][b] = (f32x4)0.f;

  const int r0 = w * 32;            // wave's staging row block
  const int lrow = l >> 2;          // 0..15
  const int lcol = (l & 3) * 8;     // 0,8,16,24
  const size_t gA = (size_t)(rb * 128 + r0 + lrow) * 1024 + lcol;
  const int lds0 = r0 * 32;
  const int lds1 = (r0 + 16) * 32;

  const int wm = (w & 1) * 64;      // wave row strip (0/64)
  const int wn = (w >> 1) * 128;    // wave col strip (0/128)
  const int lr = l & 15, ko = (l >> 4) * 8;

  // fragment-major B bases: fragRow = cb*16 + wn/16 + f, f = 0..7
  const unsigned short* Bf[8];
#pragma unroll
  for (int f = 0; f < 8; ++f)
    Bf[f] = &WFP[(size_t)(cb * 16 + (wn >> 4) + f) * 32 * 512 + l * 8];

  auto STAGE = [&](int buf, int k0) {
    gld16(&XH[gA + k0], &AH[buf][lds0]);
    gld16(&XH[gA + (size_t)16 * 1024 + k0], &AH[buf][lds1]);
    if (tp) {
      gld16(&XL[gA + k0], &AL[buf][lds0]);
      gld16(&XL[gA + (size_t)16 * 1024 + k0], &AL[buf][lds1]);
    }
  };

  STAGE(0, 0);
  int cur = 0;
  for (int ks = 0; ks < 32; ++ks) {
    // B fragments group 0 (coalesced 1KB/wave each, L2-hot)
    s16x8 bh[4];
#pragma unroll
    for (int f = 0; f < 4; ++f) bh[f] = *(const s16x8*)(Bf[f] + ks * 512);
    asm volatile("" ::: "memory");
    if (ks < 31) {
      STAGE(cur ^ 1, (ks + 1) * 32);
      // queue: [prev stage 4|2][Bg0 4][new stage 4|2] -> drain prev stage only
      if (tp) asm volatile("s_waitcnt vmcnt(8)" ::: "memory");
      else    asm volatile("s_waitcnt vmcnt(6)" ::: "memory");
    } else {
      // queue: [prev stage 4|2][Bg0 4] -> drain prev stage only
      asm volatile("s_waitcnt vmcnt(4)" ::: "memory");
    }
    __builtin_amdgcn_s_barrier();      // publish buf[cur]
    asm volatile("" ::: "memory");
    s16x8 ah[4], al[4];
#pragma unroll
    for (int f = 0; f < 4; ++f) ah[f] = *(const s16x8*)&AH[cur][(wm + f * 16 + lr) * 32 + ko];
    if (tp) {
#pragma unroll
      for (int f = 0; f < 4; ++f) al[f] = *(const s16x8*)&AL[cur][(wm + f * 16 + lr) * 32 + ko];
    }
    __builtin_amdgcn_s_setprio(1);
#pragma unroll
    for (int fa = 0; fa < 4; ++fa)
#pragma unroll
      for (int fb = 0; fb < 4; ++fb) {
        acc[fa][fb] = mfma16(ah[fa], bh[fb], acc[fa][fb]);
        if (tp) acc[fa][fb] = mfma16(al[fa], bh[fb], acc[fa][fb]);
      }
    __builtin_amdgcn_s_setprio(0);
    // B fragments group 1
    s16x8 bh2[4];
#pragma unroll
    for (int f = 0; f < 4; ++f) bh2[f] = *(const s16x8*)(Bf[4 + f] + ks * 512);
    __builtin_amdgcn_s_setprio(1);
#pragma unroll
    for (int fa = 0; fa < 4; ++fa)
#pragma unroll
      for (int fb = 0; fb < 4; ++fb) {
        acc[fa][4 + fb] = mfma16(ah[fa], bh2[fb], acc[fa][4 + fb]);
        if (tp) acc[fa][4 + fb] = mfma16(al[fa], bh2[fb], acc[fa][4 + fb]);
      }
    __builtin_amdgcn_s_setprio(0);
    asm volatile("s_waitcnt lgkmcnt(0)" ::: "memory");
    __builtin_amdgcn_s_barrier();      // buf[cur] free for restage
    asm volatile("" ::: "memory");
    cur ^= 1;
  }
  const int lg = l >> 4;
#pragma unroll
  for (int fa = 0; fa < 4; ++fa)
#pragma unroll
    for (int r = 0; r < 4; ++r) {
      int row = rb * 128 + wm + fa * 16 + lg * 4 + r;
#pragma unroll
      for (int fb = 0; fb < 8; ++fb) {
        int col = cb * 256 + wn + fb * 16 + lr;
        float v = acc[fa][fb][r];
        if (tp) {
          unsigned short hs = f2bf_rn(v);
          unsigned short ls = f2bf_rn(v - bf2f(hs));
          if (cb < 4) {
            QH[(size_t)row * 1024 + col] = hs;
            QL[(size_t)row * 1024 + col] = ls;
          } else {
            KH[(size_t)row * 1024 + col - 1024] = hs;
            KL[(size_t)row * 1024 + col - 1024] = ls;
          }
        } else {
          VB[(size_t)row * 1024 + col - 2048] = f2bf_rn(v);
        }
      }
    }
}

// -------- fused phi_k + kv: m-split x2 (z dim) [R11 proven] -----------------
__global__ __launch_bounds__(512, 1) void k_phik_kv(
    const unsigned short* __restrict__ KH, const unsigned short* __restrict__ KL,
    const unsigned short* __restrict__ VB,
    const unsigned short* __restrict__ OMB, float* __restrict__ KVP)
{
  __shared__ unsigned short KHs[64][72], KLs[64][72];
  __shared__ unsigned short PKT[128][72];
  __shared__ unsigned short AVT[80][72];
  __shared__ float norm_s[64];
  const int nc = blockIdx.x;  // 0..7
  const int bh = blockIdx.y;  // 0..31
  const int mh = blockIdx.z;  // 0..1
  const int b = bh >> 4, h = bh & 15;
  const int t = threadIdx.x, w = t >> 6, l = t & 63;
  const int lr = l & 15, lg = l >> 4, ko8 = lg * 8;
  const int mg = mh * 128 + w * 16 + lr;   // this lane's global m-column

  s16x8 omf[2];
#pragma unroll
  for (int ksub = 0; ksub < 2; ++ksub)
    omf[ksub] = *(const s16x8*)&OMB[(size_t)mg * 64 + ksub * 32 + ko8];

  for (int e = t; e < 16 * 64; e += 512) {
    int rr = e >> 6, cc = e & 63;
    AVT[64 + rr][cc] = (rr == 0) ? (unsigned short)0x3F80 : (unsigned short)0;
  }

  f32x4 acc2[5];
#pragma unroll
  for (int a = 0; a < 5; ++a) acc2[a] = (f32x4)0.f;

  for (int st = 0; st < 8; ++st) {
    const int n0 = nc * 512 + st * 64;
    __syncthreads();
    {
      int r = t >> 3, c8 = (t & 7) * 8;
      size_t o = (size_t)(b * 4096 + n0 + r) * 1024 + h * 64 + c8;
      s16x8 vh = *(const s16x8*)&KH[o];
      s16x8 vl = *(const s16x8*)&KL[o];
      *(s16x8*)&KHs[r][c8] = vh;
      *(s16x8*)&KLs[r][c8] = vl;
      float ss = 0.f;
#pragma unroll
      for (int i = 0; i < 8; ++i) {
        float q = bf2f((unsigned short)vh[i]) + bf2f((unsigned short)vl[i]);
        ss += q * q;
      }
      ss += __shfl_xor(ss, 1);
      ss += __shfl_xor(ss, 2);
      ss += __shfl_xor(ss, 4);
      if ((t & 7) == 0) norm_s[r] = 0.5f * ss;
    }
    {
      int n = t >> 3, dq = (t & 7) * 8;
      s16x8 v = *(const s16x8*)&VB[(size_t)(b * 4096 + n0 + n) * 1024 + h * 64 + dq];
#pragma unroll
      for (int i = 0; i < 8; ++i) AVT[dq + i][n] = (unsigned short)v[i];
    }
    __syncthreads();
    f32x4 acc[4];
#pragma unroll
    for (int a = 0; a < 4; ++a) acc[a] = (f32x4)0.f;
#pragma unroll
    for (int ksub = 0; ksub < 2; ++ksub) {
      int ko = ksub * 32 + ko8;
      s16x8 ah[4], al[4];
#pragma unroll
      for (int f = 0; f < 4; ++f) {
        ah[f] = *(const s16x8*)&KHs[f * 16 + lr][ko];
        al[f] = *(const s16x8*)&KLs[f * 16 + lr][ko];
      }
#pragma unroll
      for (int fa = 0; fa < 4; ++fa) {
        acc[fa] = mfma16(ah[fa], omf[ksub], acc[fa]);
        acc[fa] = mfma16(al[fa], omf[ksub], acc[fa]);
      }
    }
#pragma unroll
    for (int fa = 0; fa < 4; ++fa)
#pragma unroll
      for (int r = 0; r < 4; ++r) {
        int n = fa * 16 + lg * 4 + r;
        float nm = norm_s[n];
        int ml = w * 16 + lr;  // local m
        float p = __expf(acc[fa][r] - nm) * 0.0625f;
        PKT[ml][n] = f2bf_rn(p);
      }
    __syncthreads();
#pragma unroll
    for (int ksub = 0; ksub < 2; ++ksub) {
      int ko = ksub * 32 + ko8;
      s16x8 fA[5];
#pragma unroll
      for (int f = 0; f < 5; ++f) fA[f] = *(const s16x8*)&AVT[f * 16 + lr][ko];
      s16x8 fB = *(const s16x8*)&PKT[w * 16 + lr][ko];
#pragma unroll
      for (int fa = 0; fa < 5; ++fa) acc2[fa] = mfma16(fA[fa], fB, acc2[fa]);
    }
  }
#pragma unroll
  for (int fa = 0; fa < 5; ++fa)
#pragma unroll
    for (int r = 0; r < 4; ++r) {
      int dp = fa * 16 + lg * 4 + r;
      int m = mh * 128 + w * 16 + lr;
      KVP[(size_t)((bh * 8 + nc) * 80 + dp) * 256 + m] = acc2[fa][r];
    }
}

// reduce partials -> bf16, written FRAGMENT-MAJOR for phiq_attn's MFMA reads
__global__ __launch_bounds__(256) void k_kv_reduce(
    const float* __restrict__ KVP, unsigned short* __restrict__ KVFB)
{
  int idx = blockIdx.x * 256 + threadIdx.x;
  if (idx >= 32 * 80 * 256) return;
  int bh = idx / (80 * 256);
  int rem = idx % (80 * 256);
  int dp = rem >> 8, m = rem & 255;
  float s = 0.f;
#pragma unroll
  for (int nci = 0; nci < 8; ++nci) s += KVP[(size_t)(bh * 8 + nci) * 80 * 256 + rem];
  int kc = m >> 5, f = dp >> 4;
  int lane = (dp & 15) | (((m >> 3) & 3) << 4);
  KVFB[(((size_t)bh * 8 + kc) * 5 + f) * 512 + lane * 8 + (m & 7)] = f2bf_rn(s);
}

// ---------------- fused phi_q + attn: omega regs, kv coalesced frags --------
// ATT aliases QH plane; each (row,col) read (QH/QL) before written (ATT) by
// the same block only.
__global__ __launch_bounds__(256) void k_phiq_attn(
    const unsigned short* QH, const unsigned short* QL,
    const unsigned short* __restrict__ OMB,
    const unsigned short* __restrict__ KVFB,
    unsigned short* ATT)
{
  __shared__ unsigned short QHs[64][72], QLs[64][72];
  __shared__ unsigned short PQ[64][264];
  __shared__ float norm_s[64];
  const int nt = blockIdx.x;   // 0..63
  const int bh = blockIdx.y;   // 0..31
  const int t = threadIdx.x, w = t >> 6, l = t & 63;
  const int b = bh >> 4, h = bh & 15;
  const int lr = l & 15, lg = l >> 4, ko8 = lg * 8;

  s16x8 omf[2][4];
#pragma unroll
  for (int ksub = 0; ksub < 2; ++ksub)
#pragma unroll
    for (int f = 0; f < 4; ++f)
      omf[ksub][f] = *(const s16x8*)&OMB[(w * 64 + f * 16 + lr) * 64 + ksub * 32 + ko8];

  {
    int r = t >> 2, cq = (t & 3) * 4;
    float ss = 0.f;
#pragma unroll
    for (int j = 0; j < 4; ++j) {
      int c = cq + 16 * j;
      size_t o = (size_t)(b * 4096 + nt * 64 + r) * 1024 + h * 64 + c;
      s16x4 vh = *(const s16x4*)&QH[o];
      s16x4 vl = *(const s16x4*)&QL[o];
      *(s16x4*)&QHs[r][c] = vh;
      *(s16x4*)&QLs[r][c] = vl;
#pragma unroll
      for (int i = 0; i < 4; ++i) {
        float q = bf2f((unsigned short)vh[i]) + bf2f((unsigned short)vl[i]);
        ss += q * q;
      }
    }
    ss += __shfl_xor(ss, 1);
    ss += __shfl_xor(ss, 2);
    if ((t & 3) == 0) norm_s[r] = 0.5f * ss;
  }
  __syncthreads();
  f32x4 acc[4][4];
#pragma unroll
  for (int a = 0; a < 4; ++a)
#pragma unroll
    for (int bb = 0; bb < 4; ++bb) acc[a][bb] = (f32x4)0.f;
#pragma unroll
  for (int ksub = 0; ksub < 2; ++ksub) {
    int ko = ksub * 32 + ko8;
    s16x8 ah[4], al[4];
#pragma unroll
    for (int f = 0; f < 4; ++f) {
      ah[f] = *(const s16x8*)&QHs[f * 16 + lr][ko];
      al[f] = *(const s16x8*)&QLs[f * 16 + lr][ko];
    }
#pragma unroll
    for (int fa = 0; fa < 4; ++fa)
#pragma unroll
      for (int fb = 0; fb < 4; ++fb) {
        acc[fa][fb] = mfma16(ah[fa], omf[ksub][fb], acc[fa][fb]);
        acc[fa][fb] = mfma16(al[fa], omf[ksub][fb], acc[fa][fb]);
      }
  }
#pragma unroll
  for (int fa = 0; fa < 4; ++fa)
#pragma unroll
    for (int r = 0; r < 4; ++r) {
      int n = fa * 16 + lg * 4 + r;
      float nm = norm_s[n];
#pragma unroll
      for (int fb = 0; fb < 4; ++fb) {
        int m = w * 64 + fb * 16 + lr;
        float p = __expf(acc[fa][fb][r] - nm) * 0.0625f;
        PQ[n][m] = f2bf_rn(p);
      }
    }
  __syncthreads();
  // attn MFMA: kv fragments, fragment-major coalesced (L2-resident)
  f32x4 acc2[5];
#pragma unroll
  for (int bb = 0; bb < 5; ++bb) acc2[bb] = (f32x4)0.f;
  for (int ks = 0; ks < 8; ++ks) {
    const int m0 = ks * 32;
    s16x8 fA = *(const s16x8*)&PQ[w * 16 + lr][m0 + ko8];
    s16x8 fB[5];
#pragma unroll
    for (int f = 0; f < 5; ++f)
      fB[f] = *(const s16x8*)&KVFB[(((size_t)bh * 8 + ks) * 5 + f) * 512 + l * 8];
#pragma unroll
    for (int fb = 0; fb < 5; ++fb) acc2[fb] = mfma16(fA, fB[fb], acc2[fb]);
  }
#pragma unroll
  for (int r = 0; r < 4; ++r) {
    float den = __shfl(acc2[4][r], (l & 48));
    float z = 1.f / (den + 1e-6f);
    int n = nt * 64 + w * 16 + lg * 4 + r;
#pragma unroll
    for (int fb = 0; fb < 4; ++fb) {
      int col = h * 64 + fb * 16 + lr;
      ATT[(size_t)(b * 4096 + n) * 1024 + col] = f2bf_rn(acc2[fb][r] * z);
    }
  }
}

// ------- final GEMM: A via 2-deep LDS dbuf, B via coalesced fragments -------
__global__ __launch_bounds__(256) void k_gemm_out(
    const unsigned short* __restrict__ ATT,
    const unsigned short* __restrict__ WOFP,
    const float* __restrict__ b_o,
    float* __restrict__ OUT)
{
  __shared__ unsigned short As[2][128 * 32];
  const int flat = blockIdx.y * 8 + blockIdx.x;   // 0..511
  const int swz = (flat & 7) * 64 + (flat >> 3);  // bijective, 512 % 8 == 0
  const int cb = swz % 8;
  const int rb = swz / 8;
  const int t = threadIdx.x, w = t >> 6, l = t & 63;
  f32x4 acc[4][4];
#pragma unroll
  for (int a = 0; a < 4; ++a)
#pragma unroll
    for (int bb = 0; bb < 4; ++bb) acc[a][bb] = (f32x4)0.f;

  const int r0 = w * 32;
  const int lrow = l >> 2;
  const int lcol = (l & 3) * 8;
  const size_t gA = (size_t)(rb * 128 + r0 + lrow) * 1024 + lcol;
  const int lds0 = r0 * 32;
  const int lds1 = (r0 + 16) * 32;

  const int wm = (w & 1) * 64, wn = (w >> 1) * 64;
  const int lr = l & 15, ko = (l >> 4) * 8;

  const unsigned short* Bf[4];
#pragma unroll
  for (int f = 0; f < 4; ++f)
    Bf[f] = &WOFP[(size_t)(cb * 8 + (wn >> 4) + f) * 32 * 512 + l * 8];

  auto STAGE = [&](int buf, int k0) {
    gld16(&ATT[gA + k0], &As[buf][lds0]);
    gld16(&ATT[gA + (size_t)16 * 1024 + k0], &As[buf][lds1]);
  };

  STAGE(0, 0);
  int cur = 0;
  for (int ks = 0; ks < 32; ++ks) {
    s16x8 fB[4];
#pragma unroll
    for (int f = 0; f < 4; ++f) fB[f] = *(const s16x8*)(Bf[f] + ks * 512);
    asm volatile("" ::: "memory");
    if (ks < 31) {
      STAGE(cur ^ 1, (ks + 1) * 32);
      asm volatile("s_waitcnt vmcnt(6)" ::: "memory");  // [prev2][B4][new2]
    } else {
      asm volatile("s_waitcnt vmcnt(4)" ::: "memory");  // [prev2][B4]
    }
    __builtin_amdgcn_s_barrier();
    asm volatile("" ::: "memory");
    s16x8 fA[4];
#pragma unroll
    for (int f = 0; f < 4; ++f) fA[f] = *(const s16x8*)&As[cur][(wm + f * 16 + lr) * 32 + ko];
    __builtin_amdgcn_s_setprio(1);
#pragma unroll
    for (int fa = 0; fa < 4; ++fa)
#pragma unroll
      for (int fb = 0; fb < 4; ++fb) acc[fa][fb] = mfma16(fA[fa], fB[fb], acc[fa][fb]);
    __builtin_amdgcn_s_setprio(0);
    asm volatile("s_waitcnt lgkmcnt(0)" ::: "memory");
    __builtin_amdgcn_s_barrier();
    asm volatile("" ::: "memory");
    cur ^= 1;
  }
  const int lg = l >> 4;
#pragma unroll
  for (int fa = 0; fa < 4; ++fa)
#pragma unroll
    for (int r = 0; r < 4; ++r) {
      int row = rb * 128 + wm + fa * 16 + lg * 4 + r;
#pragma unroll
      for (int fb = 0; fb < 4; ++fb) {
        int col = cb * 128 + wn + fb * 16 + lr;
        OUT[(size_t)row * 1024 + col] = acc[fa][fb][r] + b_o[col];
      }
    }
}

extern "C" void kernel_launch(void* const* d_in, const int* in_sizes, int n_in,
                              void* d_out, int out_size, void* d_ws, size_t ws_size,
                              hipStream_t stream)
{
  const float* x  = (const float*)d_in[0];
  const float* wq = (const float*)d_in[1];
  const float* wk = (const float*)d_in[2];
  const float* wv = (const float*)d_in[3];
  const float* wo = (const float*)d_in[4];
  const float* bo = (const float*)d_in[5];
  const float* om = (const float*)d_in[6];
  float* out = (float*)d_out;

  // Workspace (~131.6 MB), identical byte layout to R12:
  const size_t PLANE = (size_t)8192 * 1024 * 2;  // 16,777,216
  char* ws = (char*)d_ws;
  unsigned short* WOFP = (unsigned short*)(ws);            // 2.1 MB
  char* segB = ws + 2097152;
  char* segC = segB + 2 * PLANE;
  char* segD = segC + 4 * PLANE;
  char* segE = segD + 26214400;

  unsigned short* QH  = (unsigned short*)segB;
  unsigned short* QL  = (unsigned short*)(segB + PLANE);
  unsigned short* ATT = (unsigned short*)segB;   // aliases QH (safe, see kernel)

  unsigned short* KH  = (unsigned short*)segC;
  unsigned short* KL  = (unsigned short*)(segC + PLANE);
  unsigned short* VB  = (unsigned short*)(segC + 2 * PLANE);
  unsigned short* XH  = (unsigned short*)(segC + 3 * PLANE);

  unsigned short* WFP = (unsigned short*)segD;             // 6.29 MB
  unsigned short* XL  = (unsigned short*)(segD + 6291456);
  float* KVP = (float*)segD;
  unsigned short* KVFB = (unsigned short*)segE;            // 1.31 MB
  unsigned short* OMB  = (unsigned short*)(segE + 1310720); // 32 KB

  k_prep_all<<<dim3(16, 16, 21), 256, 0, stream>>>(wq, wk, wv, wo, om, x,
                                                   WFP, WOFP, OMB, XH, XL);
  k_gemm_qkv<<<dim3(12, 64), 256, 0, stream>>>(XH, XL, WFP, QH, QL, KH, KL, VB);
  k_phik_kv<<<dim3(8, 32, 2), 512, 0, stream>>>(KH, KL, VB, OMB, KVP);
  k_kv_reduce<<<dim3(2560), 256, 0, stream>>>(KVP, KVFB);
  k_phiq_attn<<<dim3(64, 32), 256, 0, stream>>>(QH, QL, OMB, KVFB, ATT);
  k_gemm_out<<<dim3(8, 64), 256, 0, stream>>>(ATT, WOFP, bo, out);
}

// Round 14
// 210.782 us; speedup vs baseline: 1.3217x; 1.3217x over previous
//
#include <hip/hip_runtime.h>

#define DEVI __device__ __forceinline__

using f32x4 = __attribute__((ext_vector_type(4))) float;
using fvec4 = __attribute__((ext_vector_type(4))) float;
using s16x4 = __attribute__((ext_vector_type(4))) short;
using s16x8 = __attribute__((ext_vector_type(8))) short;

DEVI unsigned short f2bf_rn(float f) {
  union { float f; unsigned u; } v; v.f = f;
  unsigned r = v.u + 0x7fffu + ((v.u >> 16) & 1u);
  return (unsigned short)(r >> 16);
}
DEVI float bf2f(unsigned short h) {
  union { unsigned u; float f; } v; v.u = ((unsigned)h) << 16;
  return v.f;
}
DEVI f32x4 mfma16(s16x8 a, s16x8 b, f32x4 c) {
  return __builtin_amdgcn_mfma_f32_16x16x32_bf16(a, b, c, 0, 0, 0);
}
// async global->LDS, 16B per lane; lds base must be wave-uniform
DEVI void gld16(const void* g, void* lds) {
  __builtin_amdgcn_global_load_lds(
      (const __attribute__((address_space(1))) unsigned int*)g,
      (__attribute__((address_space(3))) unsigned int*)lds, 16, 0, 0);
}

// Fragment-major packing: for MFMA B-operand fragment (fragRow R/16, kChunk
// K0/32), lane l holds row R+(l&15), cols K0+(l>>4)*8..+7. Packed address:
//   P[(frag*32 + kc)*512 + lane*8 + e]
// so a wave's fragment load is 64 lanes x contiguous 16B = 1KB coalesced.

// ------- prep (merged): weights -> fragment-major bf16; omega; X split ------
__global__ __launch_bounds__(256) void k_prep_all(
    const float* __restrict__ wq, const float* __restrict__ wk,
    const float* __restrict__ wv, const float* __restrict__ wo,
    const float* __restrict__ omega, const float* __restrict__ X,
    unsigned short* __restrict__ WFP, unsigned short* __restrict__ WOFP,
    unsigned short* __restrict__ OMB,
    unsigned short* __restrict__ XH, unsigned short* __restrict__ XL)
{
  __shared__ float tile[64][65];
  const int z = blockIdx.z;
  const int t = threadIdx.x;
  if (z >= 5) {  // split X f32 -> bf16 hi/lo
    int s = z - 5;
    int bid = blockIdx.x * 16 + blockIdx.y;
    size_t i = (((size_t)s * 256 + bid) * 256 + t) * 8;
    fvec4 a = *(const fvec4*)&X[i];
    fvec4 b = *(const fvec4*)&X[i + 4];
    s16x8 hv, lv;
#pragma unroll
    for (int j = 0; j < 4; ++j) {
      unsigned short h = f2bf_rn(a[j]);
      hv[j] = (short)h; lv[j] = (short)f2bf_rn(a[j] - bf2f(h));
    }
#pragma unroll
    for (int j = 0; j < 4; ++j) {
      unsigned short h = f2bf_rn(b[j]);
      hv[4 + j] = (short)h; lv[4 + j] = (short)f2bf_rn(b[j] - bf2f(h));
    }
    *(s16x8*)&XH[i] = hv;
    *(s16x8*)&XL[i] = lv;
    return;
  }
  if (z == 4) {  // omega [256][64] f32 -> bf16 linear
    int bid = blockIdx.x * 16 + blockIdx.y;
    if (bid < 16) {
      int i = (bid * 256 + t) * 4;
      fvec4 v = *(const fvec4*)&omega[i];
      s16x4 hv;
#pragma unroll
      for (int q = 0; q < 4; ++q) hv[q] = (short)f2bf_rn(v[q]);
      *(s16x4*)&OMB[i] = hv;
    }
    return;
  }
  const float* src = (z == 0) ? wq : (z == 1) ? wk : (z == 2) ? wv : wo;
  const int k0 = blockIdx.x * 64;
  const int n0 = blockIdx.y * 64;
#pragma unroll
  for (int j = 0; j < 4; ++j) {
    int r = (t >> 4) + 16 * j;
    int c = (t & 15) * 4;
    fvec4 v = *(const fvec4*)&src[(size_t)(k0 + r) * 1024 + n0 + c];
#pragma unroll
    for (int i = 0; i < 4; ++i) tile[r][c + i] = v[i];
  }
  __syncthreads();
#pragma unroll
  for (int j = 0; j < 4; ++j) {
    int n = (t >> 4) + 16 * j;
    int kc = (t & 15) * 4;
    s16x4 hv;
#pragma unroll
    for (int i = 0; i < 4; ++i) hv[i] = (short)f2bf_rn(tile[kc + i][n]);
    const int kk = k0 + kc;
    if (z < 3) {
      int ng = z * 1024 + n0 + n;
      size_t o = ((size_t)((ng >> 4) * 32 + (kk >> 5)) * 512) +
                 (size_t)(((ng & 15) | (((kk >> 3) & 3) << 4)) * 8) + (kk & 7);
      *(s16x4*)&WFP[o] = hv;
    } else {
      int ng = n0 + n;
      size_t o = ((size_t)((ng >> 4) * 32 + (kk >> 5)) * 512) +
                 (size_t)(((ng & 15) | (((kk >> 3) & 3) << 4)) * 8) + (kk & 7);
      *(s16x4*)&WOFP[o] = hv;
    }
  }
}

// ------- QKV GEMM: A via 2-deep LDS dbuf, B via coalesced fragment loads ----
// cb<16: q,k (2-pass A-split); cb>=16: v. LDS 32KB.  [R12 proven, 122 us]
__global__ __launch_bounds__(256) void k_gemm_qkv(
    const unsigned short* __restrict__ XH, const unsigned short* __restrict__ XL,
    const unsigned short* __restrict__ WFP,
    unsigned short* __restrict__ QH, unsigned short* __restrict__ QL,
    unsigned short* __restrict__ KH, unsigned short* __restrict__ KL,
    unsigned short* __restrict__ VB)
{
  __shared__ unsigned short AH[2][128 * 32];
  __shared__ unsigned short AL[2][128 * 32];
  const int flat = blockIdx.y * 24 + blockIdx.x;   // 0..1535
  const int swz = (flat & 7) * 192 + (flat >> 3);  // bijective, 1536 % 8 == 0
  const int cb = swz % 24;
  const int rb = swz / 24;
  const int t = threadIdx.x;
  const int w = t >> 6, l = t & 63;
  const bool tp = (cb < 16);
  f32x4 acc[4][4];
#pragma unroll
  for (int a = 0; a < 4; ++a)
#pragma unroll
    for (int b = 0; b < 4; ++b) acc[a][b] = (f32x4)0.f;

  const int r0 = w * 32;            // wave's staging row block
  const int lrow = l >> 2;          // 0..15
  const int lcol = (l & 3) * 8;     // 0,8,16,24
  const size_t gA = (size_t)(rb * 128 + r0 + lrow) * 1024 + lcol;
  const int lds0 = r0 * 32;
  const int lds1 = (r0 + 16) * 32;

  const int wm = (w & 1) * 64, wn = (w >> 1) * 64;
  const int lr = l & 15, ko = (l >> 4) * 8;

  // fragment-major B base: fragRow = cb*8 + wn/16 + f
  const unsigned short* Bf[4];
#pragma unroll
  for (int f = 0; f < 4; ++f)
    Bf[f] = &WFP[(size_t)(cb * 8 + (wn >> 4) + f) * 32 * 512 + l * 8];

  auto STAGE = [&](int buf, int k0) {
    gld16(&XH[gA + k0], &AH[buf][lds0]);
    gld16(&XH[gA + (size_t)16 * 1024 + k0], &AH[buf][lds1]);
    if (tp) {
      gld16(&XL[gA + k0], &AL[buf][lds0]);
      gld16(&XL[gA + (size_t)16 * 1024 + k0], &AL[buf][lds1]);
    }
  };

  STAGE(0, 0);
  int cur = 0;
  for (int ks = 0; ks < 32; ++ks) {
    // B fragments for this step (coalesced 1KB/wave each, L2-hot)
    s16x8 bh[4];
#pragma unroll
    for (int f = 0; f < 4; ++f) bh[f] = *(const s16x8*)(Bf[f] + ks * 512);
    asm volatile("" ::: "memory");
    if (ks < 31) {
      STAGE(cur ^ 1, (ks + 1) * 32);
      // queue: [prev stage 4|2][B 4][new stage 4|2] -> drain prev stage only
      if (tp) asm volatile("s_waitcnt vmcnt(8)" ::: "memory");
      else    asm volatile("s_waitcnt vmcnt(6)" ::: "memory");
    } else {
      // queue: [prev stage 4|2][B 4] -> drain prev stage only
      asm volatile("s_waitcnt vmcnt(4)" ::: "memory");
    }
    __builtin_amdgcn_s_barrier();      // publish buf[cur]
    asm volatile("" ::: "memory");
    s16x8 ah[4], al[4];
#pragma unroll
    for (int f = 0; f < 4; ++f) ah[f] = *(const s16x8*)&AH[cur][(wm + f * 16 + lr) * 32 + ko];
    if (tp) {
#pragma unroll
      for (int f = 0; f < 4; ++f) al[f] = *(const s16x8*)&AL[cur][(wm + f * 16 + lr) * 32 + ko];
    }
    __builtin_amdgcn_s_setprio(1);
#pragma unroll
    for (int fa = 0; fa < 4; ++fa)
#pragma unroll
      for (int fb = 0; fb < 4; ++fb) {
        acc[fa][fb] = mfma16(ah[fa], bh[fb], acc[fa][fb]);
        if (tp) acc[fa][fb] = mfma16(al[fa], bh[fb], acc[fa][fb]);
      }
    __builtin_amdgcn_s_setprio(0);
    asm volatile("s_waitcnt lgkmcnt(0)" ::: "memory");
    __builtin_amdgcn_s_barrier();      // buf[cur] free for restage
    asm volatile("" ::: "memory");
    cur ^= 1;
  }
  const int lg = l >> 4;
#pragma unroll
  for (int fa = 0; fa < 4; ++fa)
#pragma unroll
    for (int r = 0; r < 4; ++r) {
      int row = rb * 128 + wm + fa * 16 + lg * 4 + r;
#pragma unroll
      for (int fb = 0; fb < 4; ++fb) {
        int col = cb * 128 + wn + fb * 16 + lr;
        float v = acc[fa][fb][r];
        if (tp) {
          unsigned short hs = f2bf_rn(v);
          unsigned short ls = f2bf_rn(v - bf2f(hs));
          if (cb < 8) {
            QH[(size_t)row * 1024 + col] = hs;
            QL[(size_t)row * 1024 + col] = ls;
          } else {
            KH[(size_t)row * 1024 + col - 1024] = hs;
            KL[(size_t)row * 1024 + col - 1024] = ls;
          }
        } else {
          VB[(size_t)row * 1024 + col - 2048] = f2bf_rn(v);
        }
      }
    }
}

// -------- fused phi_k + kv: m-split x2 (z dim) [R11 proven] -----------------
__global__ __launch_bounds__(512, 1) void k_phik_kv(
    const unsigned short* __restrict__ KH, const unsigned short* __restrict__ KL,
    const unsigned short* __restrict__ VB,
    const unsigned short* __restrict__ OMB, float* __restrict__ KVP)
{
  __shared__ unsigned short KHs[64][72], KLs[64][72];
  __shared__ unsigned short PKT[128][72];
  __shared__ unsigned short AVT[80][72];
  __shared__ float norm_s[64];
  const int nc = blockIdx.x;  // 0..7
  const int bh = blockIdx.y;  // 0..31
  const int mh = blockIdx.z;  // 0..1
  const int b = bh >> 4, h = bh & 15;
  const int t = threadIdx.x, w = t >> 6, l = t & 63;
  const int lr = l & 15, lg = l >> 4, ko8 = lg * 8;
  const int mg = mh * 128 + w * 16 + lr;   // this lane's global m-column

  s16x8 omf[2];
#pragma unroll
  for (int ksub = 0; ksub < 2; ++ksub)
    omf[ksub] = *(const s16x8*)&OMB[(size_t)mg * 64 + ksub * 32 + ko8];

  for (int e = t; e < 16 * 64; e += 512) {
    int rr = e >> 6, cc = e & 63;
    AVT[64 + rr][cc] = (rr == 0) ? (unsigned short)0x3F80 : (unsigned short)0;
  }

  f32x4 acc2[5];
#pragma unroll
  for (int a = 0; a < 5; ++a) acc2[a] = (f32x4)0.f;

  for (int st = 0; st < 8; ++st) {
    const int n0 = nc * 512 + st * 64;
    __syncthreads();
    {
      int r = t >> 3, c8 = (t & 7) * 8;
      size_t o = (size_t)(b * 4096 + n0 + r) * 1024 + h * 64 + c8;
      s16x8 vh = *(const s16x8*)&KH[o];
      s16x8 vl = *(const s16x8*)&KL[o];
      *(s16x8*)&KHs[r][c8] = vh;
      *(s16x8*)&KLs[r][c8] = vl;
      float ss = 0.f;
#pragma unroll
      for (int i = 0; i < 8; ++i) {
        float q = bf2f((unsigned short)vh[i]) + bf2f((unsigned short)vl[i]);
        ss += q * q;
      }
      ss += __shfl_xor(ss, 1);
      ss += __shfl_xor(ss, 2);
      ss += __shfl_xor(ss, 4);
      if ((t & 7) == 0) norm_s[r] = 0.5f * ss;
    }
    {
      int n = t >> 3, dq = (t & 7) * 8;
      s16x8 v = *(const s16x8*)&VB[(size_t)(b * 4096 + n0 + n) * 1024 + h * 64 + dq];
#pragma unroll
      for (int i = 0; i < 8; ++i) AVT[dq + i][n] = (unsigned short)v[i];
    }
    __syncthreads();
    f32x4 acc[4];
#pragma unroll
    for (int a = 0; a < 4; ++a) acc[a] = (f32x4)0.f;
#pragma unroll
    for (int ksub = 0; ksub < 2; ++ksub) {
      int ko = ksub * 32 + ko8;
      s16x8 ah[4], al[4];
#pragma unroll
      for (int f = 0; f < 4; ++f) {
        ah[f] = *(const s16x8*)&KHs[f * 16 + lr][ko];
        al[f] = *(const s16x8*)&KLs[f * 16 + lr][ko];
      }
#pragma unroll
      for (int fa = 0; fa < 4; ++fa) {
        acc[fa] = mfma16(ah[fa], omf[ksub], acc[fa]);
        acc[fa] = mfma16(al[fa], omf[ksub], acc[fa]);
      }
    }
#pragma unroll
    for (int fa = 0; fa < 4; ++fa)
#pragma unroll
      for (int r = 0; r < 4; ++r) {
        int n = fa * 16 + lg * 4 + r;
        float nm = norm_s[n];
        int ml = w * 16 + lr;  // local m
        float p = __expf(acc[fa][r] - nm) * 0.0625f;
        PKT[ml][n] = f2bf_rn(p);
      }
    __syncthreads();
#pragma unroll
    for (int ksub = 0; ksub < 2; ++ksub) {
      int ko = ksub * 32 + ko8;
      s16x8 fA[5];
#pragma unroll
      for (int f = 0; f < 5; ++f) fA[f] = *(const s16x8*)&AVT[f * 16 + lr][ko];
      s16x8 fB = *(const s16x8*)&PKT[w * 16 + lr][ko];
#pragma unroll
      for (int fa = 0; fa < 5; ++fa) acc2[fa] = mfma16(fA[fa], fB, acc2[fa]);
    }
  }
#pragma unroll
  for (int fa = 0; fa < 5; ++fa)
#pragma unroll
    for (int r = 0; r < 4; ++r) {
      int dp = fa * 16 + lg * 4 + r;
      int m = mh * 128 + w * 16 + lr;
      KVP[(size_t)((bh * 8 + nc) * 80 + dp) * 256 + m] = acc2[fa][r];
    }
}

// reduce partials -> bf16, written FRAGMENT-MAJOR for phiq_attn's MFMA reads
__global__ __launch_bounds__(256) void k_kv_reduce(
    const float* __restrict__ KVP, unsigned short* __restrict__ KVFB)
{
  int idx = blockIdx.x * 256 + threadIdx.x;
  if (idx >= 32 * 80 * 256) return;
  int bh = idx / (80 * 256);
  int rem = idx % (80 * 256);
  int dp = rem >> 8, m = rem & 255;
  float s = 0.f;
#pragma unroll
  for (int nci = 0; nci < 8; ++nci) s += KVP[(size_t)(bh * 8 + nci) * 80 * 256 + rem];
  int kc = m >> 5, f = dp >> 4;
  int lane = (dp & 15) | (((m >> 3) & 3) << 4);
  KVFB[(((size_t)bh * 8 + kc) * 5 + f) * 512 + lane * 8 + (m & 7)] = f2bf_rn(s);
}

// ---------------- fused phi_q + attn: omega regs, kv coalesced frags --------
// ATT aliases QH plane; each (row,col) read (QH/QL) before written (ATT) by
// the same block only.
__global__ __launch_bounds__(256) void k_phiq_attn(
    const unsigned short* QH, const unsigned short* QL,
    const unsigned short* __restrict__ OMB,
    const unsigned short* __restrict__ KVFB,
    unsigned short* ATT)
{
  __shared__ unsigned short QHs[64][72], QLs[64][72];
  __shared__ unsigned short PQ[64][264];
  __shared__ float norm_s[64];
  const int nt = blockIdx.x;   // 0..63
  const int bh = blockIdx.y;   // 0..31
  const int t = threadIdx.x, w = t >> 6, l = t & 63;
  const int b = bh >> 4, h = bh & 15;
  const int lr = l & 15, lg = l >> 4, ko8 = lg * 8;

  s16x8 omf[2][4];
#pragma unroll
  for (int ksub = 0; ksub < 2; ++ksub)
#pragma unroll
    for (int f = 0; f < 4; ++f)
      omf[ksub][f] = *(const s16x8*)&OMB[(w * 64 + f * 16 + lr) * 64 + ksub * 32 + ko8];

  {
    int r = t >> 2, cq = (t & 3) * 4;
    float ss = 0.f;
#pragma unroll
    for (int j = 0; j < 4; ++j) {
      int c = cq + 16 * j;
      size_t o = (size_t)(b * 4096 + nt * 64 + r) * 1024 + h * 64 + c;
      s16x4 vh = *(const s16x4*)&QH[o];
      s16x4 vl = *(const s16x4*)&QL[o];
      *(s16x4*)&QHs[r][c] = vh;
      *(s16x4*)&QLs[r][c] = vl;
#pragma unroll
      for (int i = 0; i < 4; ++i) {
        float q = bf2f((unsigned short)vh[i]) + bf2f((unsigned short)vl[i]);
        ss += q * q;
      }
    }
    ss += __shfl_xor(ss, 1);
    ss += __shfl_xor(ss, 2);
    if ((t & 3) == 0) norm_s[r] = 0.5f * ss;
  }
  __syncthreads();
  f32x4 acc[4][4];
#pragma unroll
  for (int a = 0; a < 4; ++a)
#pragma unroll
    for (int bb = 0; bb < 4; ++bb) acc[a][bb] = (f32x4)0.f;
#pragma unroll
  for (int ksub = 0; ksub < 2; ++ksub) {
    int ko = ksub * 32 + ko8;
    s16x8 ah[4], al[4];
#pragma unroll
    for (int f = 0; f < 4; ++f) {
      ah[f] = *(const s16x8*)&QHs[f * 16 + lr][ko];
      al[f] = *(const s16x8*)&QLs[f * 16 + lr][ko];
    }
#pragma unroll
    for (int fa = 0; fa < 4; ++fa)
#pragma unroll
      for (int fb = 0; fb < 4; ++fb) {
        acc[fa][fb] = mfma16(ah[fa], omf[ksub][fb], acc[fa][fb]);
        acc[fa][fb] = mfma16(al[fa], omf[ksub][fb], acc[fa][fb]);
      }
  }
#pragma unroll
  for (int fa = 0; fa < 4; ++fa)
#pragma unroll
    for (int r = 0; r < 4; ++r) {
      int n = fa * 16 + lg * 4 + r;
      float nm = norm_s[n];
#pragma unroll
      for (int fb = 0; fb < 4; ++fb) {
        int m = w * 64 + fb * 16 + lr;
        float p = __expf(acc[fa][fb][r] - nm) * 0.0625f;
        PQ[n][m] = f2bf_rn(p);
      }
    }
  __syncthreads();
  // attn MFMA: kv fragments, fragment-major coalesced (L2-resident)
  f32x4 acc2[5];
#pragma unroll
  for (int bb = 0; bb < 5; ++bb) acc2[bb] = (f32x4)0.f;
  for (int ks = 0; ks < 8; ++ks) {
    const int m0 = ks * 32;
    s16x8 fA = *(const s16x8*)&PQ[w * 16 + lr][m0 + ko8];
    s16x8 fB[5];
#pragma unroll
    for (int f = 0; f < 5; ++f)
      fB[f] = *(const s16x8*)&KVFB[(((size_t)bh * 8 + ks) * 5 + f) * 512 + l * 8];
#pragma unroll
    for (int fb = 0; fb < 5; ++fb) acc2[fb] = mfma16(fA, fB[fb], acc2[fb]);
  }
#pragma unroll
  for (int r = 0; r < 4; ++r) {
    float den = __shfl(acc2[4][r], (l & 48));
    float z = 1.f / (den + 1e-6f);
    int n = nt * 64 + w * 16 + lg * 4 + r;
#pragma unroll
    for (int fb = 0; fb < 4; ++fb) {
      int col = h * 64 + fb * 16 + lr;
      ATT[(size_t)(b * 4096 + n) * 1024 + col] = f2bf_rn(acc2[fb][r] * z);
    }
  }
}

// ------- final GEMM: A via 2-deep LDS dbuf, B via coalesced fragments -------
__global__ __launch_bounds__(256) void k_gemm_out(
    const unsigned short* __restrict__ ATT,
    const unsigned short* __restrict__ WOFP,
    const float* __restrict__ b_o,
    float* __restrict__ OUT)
{
  __shared__ unsigned short As[2][128 * 32];
  const int flat = blockIdx.y * 8 + blockIdx.x;   // 0..511
  const int swz = (flat & 7) * 64 + (flat >> 3);  // bijective, 512 % 8 == 0
  const int cb = swz % 8;
  const int rb = swz / 8;
  const int t = threadIdx.x, w = t >> 6, l = t & 63;
  f32x4 acc[4][4];
#pragma unroll
  for (int a = 0; a < 4; ++a)
#pragma unroll
    for (int bb = 0; bb < 4; ++bb) acc[a][bb] = (f32x4)0.f;

  const int r0 = w * 32;
  const int lrow = l >> 2;
  const int lcol = (l & 3) * 8;
  const size_t gA = (size_t)(rb * 128 + r0 + lrow) * 1024 + lcol;
  const int lds0 = r0 * 32;
  const int lds1 = (r0 + 16) * 32;

  const int wm = (w & 1) * 64, wn = (w >> 1) * 64;
  const int lr = l & 15, ko = (l >> 4) * 8;

  const unsigned short* Bf[4];
#pragma unroll
  for (int f = 0; f < 4; ++f)
    Bf[f] = &WOFP[(size_t)(cb * 8 + (wn >> 4) + f) * 32 * 512 + l * 8];

  auto STAGE = [&](int buf, int k0) {
    gld16(&ATT[gA + k0], &As[buf][lds0]);
    gld16(&ATT[gA + (size_t)16 * 1024 + k0], &As[buf][lds1]);
  };

  STAGE(0, 0);
  int cur = 0;
  for (int ks = 0; ks < 32; ++ks) {
    s16x8 fB[4];
#pragma unroll
    for (int f = 0; f < 4; ++f) fB[f] = *(const s16x8*)(Bf[f] + ks * 512);
    asm volatile("" ::: "memory");
    if (ks < 31) {
      STAGE(cur ^ 1, (ks + 1) * 32);
      asm volatile("s_waitcnt vmcnt(6)" ::: "memory");  // [prev2][B4][new2]
    } else {
      asm volatile("s_waitcnt vmcnt(4)" ::: "memory");  // [prev2][B4]
    }
    __builtin_amdgcn_s_barrier();
    asm volatile("" ::: "memory");
    s16x8 fA[4];
#pragma unroll
    for (int f = 0; f < 4; ++f) fA[f] = *(const s16x8*)&As[cur][(wm + f * 16 + lr) * 32 + ko];
    __builtin_amdgcn_s_setprio(1);
#pragma unroll
    for (int fa = 0; fa < 4; ++fa)
#pragma unroll
      for (int fb = 0; fb < 4; ++fb) acc[fa][fb] = mfma16(fA[fa], fB[fb], acc[fa][fb]);
    __builtin_amdgcn_s_setprio(0);
    asm volatile("s_waitcnt lgkmcnt(0)" ::: "memory");
    __builtin_amdgcn_s_barrier();
    asm volatile("" ::: "memory");
    cur ^= 1;
  }
  const int lg = l >> 4;
#pragma unroll
  for (int fa = 0; fa < 4; ++fa)
#pragma unroll
    for (int r = 0; r < 4; ++r) {
      int row = rb * 128 + wm + fa * 16 + lg * 4 + r;
#pragma unroll
      for (int fb = 0; fb < 4; ++fb) {
        int col = cb * 128 + wn + fb * 16 + lr;
        OUT[(size_t)row * 1024 + col] = acc[fa][fb][r] + b_o[col];
      }
    }
}

extern "C" void kernel_launch(void* const* d_in, const int* in_sizes, int n_in,
                              void* d_out, int out_size, void* d_ws, size_t ws_size,
                              hipStream_t stream)
{
  const float* x  = (const float*)d_in[0];
  const float* wq = (const float*)d_in[1];
  const float* wk = (const float*)d_in[2];
  const float* wv = (const float*)d_in[3];
  const float* wo = (const float*)d_in[4];
  const float* bo = (const float*)d_in[5];
  const float* om = (const float*)d_in[6];
  float* out = (float*)d_out;

  // Workspace (~131.6 MB), identical byte layout to R12:
  const size_t PLANE = (size_t)8192 * 1024 * 2;  // 16,777,216
  char* ws = (char*)d_ws;
  unsigned short* WOFP = (unsigned short*)(ws);            // 2.1 MB
  char* segB = ws + 2097152;
  char* segC = segB + 2 * PLANE;
  char* segD = segC + 4 * PLANE;
  char* segE = segD + 26214400;

  unsigned short* QH  = (unsigned short*)segB;
  unsigned short* QL  = (unsigned short*)(segB + PLANE);
  unsigned short* ATT = (unsigned short*)segB;   // aliases QH (safe, see kernel)

  unsigned short* KH  = (unsigned short*)segC;
  unsigned short* KL  = (unsigned short*)(segC + PLANE);
  unsigned short* VB  = (unsigned short*)(segC + 2 * PLANE);
  unsigned short* XH  = (unsigned short*)(segC + 3 * PLANE);

  unsigned short* WFP = (unsigned short*)segD;             // 6.29 MB
  unsigned short* XL  = (unsigned short*)(segD + 6291456);
  float* KVP = (float*)segD;
  unsigned short* KVFB = (unsigned short*)segE;            // 1.31 MB
  unsigned short* OMB  = (unsigned short*)(segE + 1310720); // 32 KB

  k_prep_all<<<dim3(16, 16, 21), 256, 0, stream>>>(wq, wk, wv, wo, om, x,
                                                   WFP, WOFP, OMB, XH, XL);
  k_gemm_qkv<<<dim3(24, 64), 256, 0, stream>>>(XH, XL, WFP, QH, QL, KH, KL, VB);
  k_phik_kv<<<dim3(8, 32, 2), 512, 0, stream>>>(KH, KL, VB, OMB, KVP);
  k_kv_reduce<<<dim3(2560), 256, 0, stream>>>(KVP, KVFB);
  k_phiq_attn<<<dim3(64, 32), 256, 0, stream>>>(QH, QL, OMB, KVFB, ATT);
  k_gemm_out<<<dim3(8, 64), 256, 0, stream>>>(ATT, WOFP, bo, out);
}